// Round 1
// baseline (739.325 us; speedup 1.0000x reference)
//
#include <hip/hip_runtime.h>
#include <math.h>

// Problem constants
#define BB   8
#define CC   64
#define NN   16384      // H*W
#define EE   3
#define NHEAD 16

// ws layout (float offsets)
#define OFF_XG    0          // 512  (B*C channel sums, atomically accumulated)
#define OFF_COV   512        // 8*64*64 = 32768 (per-batch covariance, atomic)
#define OFF_LOGIT 33280      // 24   (B*E relu gate)
#define OFF_MV    33312      // 3*8*64*64 = 98304 (attn-folded Wv per (e,b))

// out layout (float offsets)
#define OUT_HID   8388608
#define OUT_LOGIT 8388736

// ---------------------------------------------------------------------------
// Kernel 1: per-batch covariance Cov[b] = X X^T and channel sums (for mean)
// grid: 512 = B * 64 slices of 256 pixels, block: 256
// ---------------------------------------------------------------------------
__global__ __launch_bounds__(256) void cov_kernel(const float* __restrict__ x,
                                                  float* __restrict__ ws) {
    __shared__ float xs[256][65];          // [pixel][channel], stride 65 kills conflicts
    const int t = threadIdx.x;
    const int b = blockIdx.x >> 6;
    const int slice = blockIdx.x & 63;
    const float* xb = x + (size_t)b * CC * NN + slice * 256;

    for (int k = 0; k < 64; ++k)           // channel k, lanes = consecutive pixels
        xs[t][k] = xb[k * NN + t];
    __syncthreads();

    const int tr = (t >> 4) << 2;          // 4 rows of Cov owned by this thread
    const int tc = (t & 15) << 2;          // 4 cols
    float a00=0,a01=0,a02=0,a03=0, a10=0,a11=0,a12=0,a13=0;
    float a20=0,a21=0,a22=0,a23=0, a30=0,a31=0,a32=0,a33=0;
    for (int p = 0; p < 256; ++p) {
        const float* row = &xs[p][0];
        float r0=row[tr], r1=row[tr+1], r2=row[tr+2], r3=row[tr+3];
        float c0=row[tc], c1=row[tc+1], c2=row[tc+2], c3=row[tc+3];
        a00 += r0*c0; a01 += r0*c1; a02 += r0*c2; a03 += r0*c3;
        a10 += r1*c0; a11 += r1*c1; a12 += r1*c2; a13 += r1*c3;
        a20 += r2*c0; a21 += r2*c1; a22 += r2*c2; a23 += r2*c3;
        a30 += r3*c0; a31 += r3*c1; a32 += r3*c2; a33 += r3*c3;
    }
    float* cov = ws + OFF_COV + b * 4096;
    atomicAdd(&cov[(tr+0)*64 + tc+0], a00); atomicAdd(&cov[(tr+0)*64 + tc+1], a01);
    atomicAdd(&cov[(tr+0)*64 + tc+2], a02); atomicAdd(&cov[(tr+0)*64 + tc+3], a03);
    atomicAdd(&cov[(tr+1)*64 + tc+0], a10); atomicAdd(&cov[(tr+1)*64 + tc+1], a11);
    atomicAdd(&cov[(tr+1)*64 + tc+2], a12); atomicAdd(&cov[(tr+1)*64 + tc+3], a13);
    atomicAdd(&cov[(tr+2)*64 + tc+0], a20); atomicAdd(&cov[(tr+2)*64 + tc+1], a21);
    atomicAdd(&cov[(tr+2)*64 + tc+2], a22); atomicAdd(&cov[(tr+2)*64 + tc+3], a23);
    atomicAdd(&cov[(tr+3)*64 + tc+0], a30); atomicAdd(&cov[(tr+3)*64 + tc+1], a31);
    atomicAdd(&cov[(tr+3)*64 + tc+2], a32); atomicAdd(&cov[(tr+3)*64 + tc+3], a33);

    if (t < 64) {                          // channel sums for x_global
        float s = 0.f;
        for (int p = 0; p < 256; ++p) s += xs[p][t];
        atomicAdd(ws + OFF_XG + b * 64 + t, s);
    }
}

// ---------------------------------------------------------------------------
// Kernel 2: routing MLP. 1 block, 128 threads.
// ---------------------------------------------------------------------------
__global__ __launch_bounds__(128) void route_kernel(const float* __restrict__ hidden,
        const float* __restrict__ r1w, const float* __restrict__ r1b,
        const float* __restrict__ r3w, const float* __restrict__ r3b,
        float* __restrict__ ws, float* __restrict__ out) {
    __shared__ float hn[128];
    const int t = threadIdx.x;
    {
        const int b = t >> 4, j = t & 15;
        const float* xg = ws + OFF_XG + b * 64;
        float s = r1b[j];
        for (int c = 0; c < 64; ++c) s += r1w[j*80 + c] * (xg[c] * (1.0f/16384.0f));
        for (int k = 0; k < 16; ++k) s += r1w[j*80 + 64 + k] * hidden[b*16 + k];
        // exact gelu: 0.5*x*(1+erf(x/sqrt(2)))
        float g = 0.5f * s * (1.0f + erff(s * 0.70710678118654752440f));
        hn[t] = g;
        out[OUT_HID + t] = g;
    }
    __syncthreads();
    if (t < 24) {
        const int b = t / 3, e = t - b * 3;
        float s = r3b[e];
        for (int j = 0; j < 16; ++j) s += r3w[e*16 + j] * hn[b*16 + j];
        s = fmaxf(s, 0.0f);
        ws[OFF_LOGIT + t] = s;
        out[OUT_LOGIT + t] = s;
    }
}

// ---------------------------------------------------------------------------
// Kernel 3: attention finalize. grid 24 = (e,b), block 256.
// Computes per-head 4x4 softmax attn from Cov, folds into Wv -> Mv[e][b].
// ---------------------------------------------------------------------------
__global__ __launch_bounds__(256) void attn_kernel(const float* __restrict__ qkv_w,
        const float* __restrict__ temp, float* __restrict__ ws) {
    __shared__ float Wl[192 * 65];
    __shared__ float Cv[64 * 65];
    __shared__ float TQ[64 * 65];
    __shared__ float TK[64 * 65];
    __shared__ float qkb[256];
    __shared__ float qqb[64];
    __shared__ float kkb[64];
    __shared__ float atl[256];
    const int t = threadIdx.x;
    const int e = blockIdx.x >> 3, b = blockIdx.x & 7;
    const float lg = ws[OFF_LOGIT + b * 3 + e];
    if (!(lg > 0.0f)) return;              // gated off: contribution is exactly 0

    for (int idx = t; idx < 12288; idx += 256)
        Wl[(idx >> 6) * 65 + (idx & 63)] = qkv_w[e * 12288 + idx];
    for (int idx = t; idx < 4096; idx += 256)
        Cv[(idx >> 6) * 65 + (idx & 63)] = ws[OFF_COV + b * 4096 + idx];
    __syncthreads();

    {   // TQ = Wq*Cov, TK = Wk*Cov
        const int r = t >> 2, cq = (t & 3) << 4;
        float aq[16], ak[16];
        #pragma unroll
        for (int i = 0; i < 16; ++i) { aq[i] = 0.f; ak[i] = 0.f; }
        for (int c1 = 0; c1 < 64; ++c1) {
            float wq = Wl[r * 65 + c1];
            float wk = Wl[(64 + r) * 65 + c1];
            #pragma unroll
            for (int i = 0; i < 16; ++i) {
                float cv = Cv[c1 * 65 + cq + i];
                aq[i] += wq * cv; ak[i] += wk * cv;
            }
        }
        #pragma unroll
        for (int i = 0; i < 16; ++i) { TQ[r*65 + cq + i] = aq[i]; TK[r*65 + cq + i] = ak[i]; }
    }
    __syncthreads();

    for (int idx = t; idx < 384; idx += 256) {   // per-head gram entries
        const int h = idx / 24, u = idx - h * 24;
        float s = 0.f;
        if (u < 16) {
            const int i = u >> 2, j = u & 3;
            const float* tq = &TQ[(4*h + i) * 65];
            const float* wk = &Wl[(64 + 4*h + j) * 65];
            for (int c = 0; c < 64; ++c) s += tq[c] * wk[c];
            qkb[h * 16 + u] = s;
        } else if (u < 20) {
            const int i = u - 16;
            const float* tq = &TQ[(4*h + i) * 65];
            const float* wq = &Wl[(4*h + i) * 65];
            for (int c = 0; c < 64; ++c) s += tq[c] * wq[c];
            qqb[h * 4 + i] = s;
        } else {
            const int j = u - 20;
            const float* tk = &TK[(4*h + j) * 65];
            const float* wk = &Wl[(64 + 4*h + j) * 65];
            for (int c = 0; c < 64; ++c) s += tk[c] * wk[c];
            kkb[h * 4 + j] = s;
        }
    }
    __syncthreads();

    if (t < 64) {                           // softmax over j (4-wide)
        const int h = t >> 2, i = t & 3;
        const float tp = temp[e * 16 + h];
        const float rq = 1.0f / fmaxf(sqrtf(qqb[h*4 + i]), 1e-12f);
        float l[4];
        #pragma unroll
        for (int j = 0; j < 4; ++j) {
            float rk = 1.0f / fmaxf(sqrtf(kkb[h*4 + j]), 1e-12f);
            l[j] = qkb[h*16 + i*4 + j] * rq * rk * tp;
        }
        float m = fmaxf(fmaxf(l[0], l[1]), fmaxf(l[2], l[3]));
        float ex[4]; float s = 0.f;
        #pragma unroll
        for (int j = 0; j < 4; ++j) { ex[j] = expf(l[j] - m); s += ex[j]; }
        float inv = 1.0f / s;
        #pragma unroll
        for (int j = 0; j < 4; ++j) atl[h*16 + i*4 + j] = ex[j] * inv;
    }
    __syncthreads();

    // Mv[o][c] = sum_j attn[h(o)][o%4][j] * Wv[4h+j][c]
    float* mv = ws + OFF_MV + (size_t)blockIdx.x * 4096;
    for (int idx = t; idx < 4096; idx += 256) {
        const int o = idx >> 6, c = idx & 63;
        const int h = o >> 2, ii = o & 3;
        float s = 0.f;
        #pragma unroll
        for (int j = 0; j < 4; ++j)
            s += atl[h*16 + ii*4 + j] * Wl[(128 + 4*h + j) * 65 + c];
        mv[idx] = s;
    }
}

// ---------------------------------------------------------------------------
// Kernel 4: fused  v' = Mv@x  ->  depthwise 3x3  ->  (logit*proj) @ .  summed
// over experts. grid (100 tiles, 8 batches), block 256 = 16x16 staging region
// (1-px halo), inner 14x14 outputs. x column + output accumulator in regs.
// ---------------------------------------------------------------------------
__global__ __launch_bounds__(256) void pass2_kernel(const float* __restrict__ x,
        const float* __restrict__ dw_w, const float* __restrict__ proj_w,
        const float* __restrict__ ws, float* __restrict__ out) {
    __shared__ float vbuf[64][256];   // v' tile  [channel][pixel-in-16x16]
    __shared__ float wlds[64 * 68];   // Mv (phase A, [o][c]) or projT*lg (phase B, [c][o])
    __shared__ float dwlds[64 * 12];  // depthwise weights, padded 9->12

    const int t = threadIdx.x;
    const int b = blockIdx.y;
    const int tile = blockIdx.x;
    const int ty = tile / 10, tx = tile - ty * 10;
    const int py = t >> 4, px = t & 15;
    const int gy = ty * 14 - 1 + py;
    const int gx = tx * 14 - 1 + px;
    const bool inimg = (gy >= 0 && gy < 128 && gx >= 0 && gx < 128);
    const int pix = (gy << 7) + gx;
    const float* xb = x + ((size_t)b << 20);

    float xcol[64];
    #pragma unroll
    for (int c = 0; c < 64; ++c) xcol[c] = inimg ? xb[(c << 14) + pix] : 0.0f;

    float outacc[64];
    #pragma unroll
    for (int o = 0; o < 64; ++o) outacc[o] = 0.0f;

    // clamped dwconv neighbor offsets (border threads compute garbage, unused)
    int off[9];
    #pragma unroll
    for (int ky = 0; ky < 3; ++ky)
        #pragma unroll
        for (int kx = 0; kx < 3; ++kx) {
            int p = (py + ky - 1) * 16 + (px + kx - 1);
            off[ky * 3 + kx] = p < 0 ? 0 : (p > 255 ? 255 : p);
        }

    for (int e = 0; e < 3; ++e) {
        const float lg = ws[OFF_LOGIT + b * 3 + e];
        if (!(lg > 0.0f)) continue;       // uniform per block: safe with barriers

        __syncthreads();                  // protect wlds/vbuf from previous phase readers
        const float* mv = ws + OFF_MV + (size_t)(e * 8 + b) * 4096;
        for (int idx = t; idx < 4096; idx += 256)
            wlds[(idx >> 6) * 68 + (idx & 63)] = mv[idx];
        __syncthreads();

        // phase A: v'[o] = Mv[o]·xcol
        for (int o = 0; o < 64; ++o) {
            const float4* m4 = (const float4*)&wlds[o * 68];
            float s0 = 0.f, s1 = 0.f, s2 = 0.f, s3 = 0.f;
            #pragma unroll
            for (int c4 = 0; c4 < 16; ++c4) {
                float4 m = m4[c4];
                s0 += m.x * xcol[4*c4 + 0];
                s1 += m.y * xcol[4*c4 + 1];
                s2 += m.z * xcol[4*c4 + 2];
                s3 += m.w * xcol[4*c4 + 3];
            }
            vbuf[o][t] = (s0 + s1) + (s2 + s3);
        }
        __syncthreads();                  // vbuf ready, done reading wlds

        // stage projT * logit and dw weights
        for (int idx = t; idx < 4096; idx += 256) {
            const int c = idx >> 6, o = idx & 63;
            wlds[c * 68 + o] = proj_w[e * 4096 + o * 64 + c] * lg;
        }
        for (int idx = t; idx < 576; idx += 256)
            dwlds[(idx / 9) * 12 + (idx % 9)] = dw_w[e * 576 + idx];
        __syncthreads();

        // phase B: per channel: depthwise then rank-1 update of outacc
        for (int c = 0; c < 64; ++c) {
            const float* dwc = &dwlds[c * 12];
            const float* vr = &vbuf[c][0];
            float dc = 0.f;
            #pragma unroll
            for (int k = 0; k < 9; ++k) dc += dwc[k] * vr[off[k]];
            const float4* pw4 = (const float4*)&wlds[c * 68];
            #pragma unroll
            for (int o4 = 0; o4 < 16; ++o4) {
                float4 pw = pw4[o4];
                outacc[4*o4 + 0] += pw.x * dc;
                outacc[4*o4 + 1] += pw.y * dc;
                outacc[4*o4 + 2] += pw.z * dc;
                outacc[4*o4 + 3] += pw.w * dc;
            }
        }
    }

    const bool store = inimg && py >= 1 && py <= 14 && px >= 1 && px <= 14;
    if (store) {
        float* ob = out + ((size_t)b << 20) + pix;
        #pragma unroll
        for (int o = 0; o < 64; ++o) ob[(size_t)o << 14] = outacc[o];
    }
}

// ---------------------------------------------------------------------------
extern "C" void kernel_launch(void* const* d_in, const int* in_sizes, int n_in,
                              void* d_out, int out_size, void* d_ws, size_t ws_size,
                              hipStream_t stream) {
    const float* x      = (const float*)d_in[0];
    const float* hidden = (const float*)d_in[1];
    const float* qkv_w  = (const float*)d_in[2];
    const float* dw_w   = (const float*)d_in[3];
    const float* proj_w = (const float*)d_in[4];
    const float* temp   = (const float*)d_in[5];
    const float* r1w    = (const float*)d_in[6];
    const float* r1b    = (const float*)d_in[7];
    const float* r3w    = (const float*)d_in[8];
    const float* r3b    = (const float*)d_in[9];
    float* out = (float*)d_out;
    float* ws  = (float*)d_ws;

    // zero the atomic-accumulated regions (ws is poisoned 0xAA before each call)
    hipMemsetAsync(ws, 0, (size_t)(512 + 32768) * sizeof(float), stream);

    cov_kernel  <<<dim3(512),      dim3(256), 0, stream>>>(x, ws);
    route_kernel<<<dim3(1),        dim3(128), 0, stream>>>(hidden, r1w, r1b, r3w, r3b, ws, out);
    attn_kernel <<<dim3(24),       dim3(256), 0, stream>>>(qkv_w, temp, ws);
    pass2_kernel<<<dim3(100, 8),   dim3(256), 0, stream>>>(x, dw_w, proj_w, ws, out);
}

// Round 3
// 222.001 us; speedup vs baseline: 3.3303x; 3.3303x over previous
//
#include <hip/hip_runtime.h>
#include <math.h>

// Problem constants
#define BB   8
#define CC   64
#define NN   16384      // H*W
#define EE   3
#define NHEAD 16

// ws layout (float offsets)
#define OFF_XG    0          // 512  (B*C channel sums, atomically accumulated)
#define OFF_COV   512        // 8*64*64 = 32768 (per-batch covariance, upper-tri written, atomic)
#define OFF_LOGIT 33280      // 24   (B*E relu gate)
#define OFF_MV    33312      // 3*8*64*64 = 98304 fp32 (attn-folded Wv per (e,b))
#define OFF_H_BYTES 526464   // byte offset: H[b][64][576] bf16 = 589824 bytes

// out layout (float offsets)
#define OUT_HID   8388608
#define OUT_LOGIT 8388736

typedef __attribute__((ext_vector_type(8))) short bf16x8;
typedef __attribute__((ext_vector_type(4))) float f32x4;

__device__ inline unsigned short f2bf(float f) {
    union { float f; unsigned int u; } v; v.f = f;
    return (unsigned short)((v.u + 0x7FFFu + ((v.u >> 16) & 1u)) >> 16);
}
__device__ inline float bf2f(unsigned short h) {
    union { unsigned int u; float f; } v; v.u = ((unsigned int)h) << 16;
    return v.f;
}

// ---------------------------------------------------------------------------
// Kernel 1: MFMA Gram: Cov[b] = X X^T (upper-tri blocks) + channel sums.
// grid 256 = 8 b x 32 chunks (512 px each), block 256 (4 waves).
// A-frag == B-frag (same registers), 10 upper frags of 16.
// ---------------------------------------------------------------------------
__global__ __launch_bounds__(256) void cov_kernel(const float* __restrict__ x,
                                                  float* __restrict__ ws) {
    __shared__ unsigned short xl[64 * 520];   // [c][512 px], pitch 520 (2-way max)
    const int t = threadIdx.x;
    const int w = t >> 6, l = t & 63;
    const int b = blockIdx.x >> 5;
    const int chunk = blockIdx.x & 31;
    const float* xb = x + ((size_t)b << 20) + (chunk << 9);

    // stage 512px x 64ch fp32 -> bf16, coalesced float4
    for (int i = 0; i < 32; ++i) {
        const int idx = i * 256 + t;
        const int c = idx >> 7, u = idx & 127;
        const float4 v = *(const float4*)(xb + ((size_t)c << 14) + (u << 2));
        unsigned long long pk = (unsigned long long)f2bf(v.x)
                              | ((unsigned long long)f2bf(v.y) << 16)
                              | ((unsigned long long)f2bf(v.z) << 32)
                              | ((unsigned long long)f2bf(v.w) << 48);
        *(unsigned long long*)&xl[c * 520 + (u << 2)] = pk;
    }
    __syncthreads();

    // channel partial sums for x_global (bf16-rounded; error ~1e-6, fine)
    {
        const int c = t & 63, q = t >> 6;
        float s = 0.f;
        for (int u = 0; u < 16; ++u) {
            const unsigned short* p = &xl[c * 520 + q * 128 + u * 8];
            #pragma unroll
            for (int j = 0; j < 8; ++j) s += bf2f(p[j]);
        }
        atomicAdd(ws + OFF_XG + b * 64 + c, s);
    }

    f32x4 acc[10];
    const f32x4 fz = {0.f, 0.f, 0.f, 0.f};
    #pragma unroll
    for (int q = 0; q < 10; ++q) acc[q] = fz;

    const int lane_a = (l & 15) * 520 + (l >> 4) * 8;
    #pragma unroll
    for (int ks = 0; ks < 4; ++ks) {
        const int p0 = w * 128 + ks * 32;
        bf16x8 fr[4];
        #pragma unroll
        for (int mi = 0; mi < 4; ++mi)
            fr[mi] = *(const bf16x8*)&xl[mi * 16 * 520 + p0 + lane_a];
        int q = 0;
        #pragma unroll
        for (int mi = 0; mi < 4; ++mi)
            #pragma unroll
            for (int ni = mi; ni < 4; ++ni) {
                acc[q] = __builtin_amdgcn_mfma_f32_16x16x32_bf16(fr[mi], fr[ni], acc[q], 0, 0, 0);
                ++q;
            }
    }
    __syncthreads();

    // cross-wave reduce in LDS (alias xl), then atomics (upper blocks only)
    float* red = (float*)xl;
    #pragma unroll
    for (int q = 0; q < 10; ++q)
        #pragma unroll
        for (int j = 0; j < 4; ++j)
            red[w * 2560 + q * 256 + ((l >> 4) * 4 + j) * 16 + (l & 15)] = acc[q][j];
    __syncthreads();

    const int MI[10] = {0,0,0,0,1,1,1,2,2,3};
    const int NI[10] = {0,1,2,3,1,2,3,2,3,3};
    #pragma unroll
    for (int k = 0; k < 10; ++k) {
        const int i = k * 256 + t;
        const float s = red[i] + red[2560 + i] + red[5120 + i] + red[7680 + i];
        const int r = MI[k] * 16 + (t >> 4), c = NI[k] * 16 + (t & 15);
        atomicAdd(ws + OFF_COV + b * 4096 + r * 64 + c, s);
    }
}

// ---------------------------------------------------------------------------
// Kernel 2: routing MLP. 1 block, 128 threads. (fp32 exact path)
// ---------------------------------------------------------------------------
__global__ __launch_bounds__(128) void route_kernel(const float* __restrict__ hidden,
        const float* __restrict__ r1w, const float* __restrict__ r1b,
        const float* __restrict__ r3w, const float* __restrict__ r3b,
        float* __restrict__ ws, float* __restrict__ out) {
    __shared__ float hn[128];
    const int t = threadIdx.x;
    {
        const int b = t >> 4, j = t & 15;
        const float* xg = ws + OFF_XG + b * 64;
        float s = r1b[j];
        for (int c = 0; c < 64; ++c) s += r1w[j*80 + c] * (xg[c] * (1.0f/16384.0f));
        for (int k = 0; k < 16; ++k) s += r1w[j*80 + 64 + k] * hidden[b*16 + k];
        float g = 0.5f * s * (1.0f + erff(s * 0.70710678118654752440f));
        hn[t] = g;
        out[OUT_HID + t] = g;
    }
    __syncthreads();
    if (t < 24) {
        const int b = t / 3, e = t - b * 3;
        float s = r3b[e];
        for (int j = 0; j < 16; ++j) s += r3w[e*16 + j] * hn[b*16 + j];
        s = fmaxf(s, 0.0f);
        ws[OFF_LOGIT + t] = s;
        out[OUT_LOGIT + t] = s;
    }
}

// ---------------------------------------------------------------------------
// Kernel 3: attention finalize. grid 24 = (e,b), block 256.
// Per-head 4x4 softmax attn from Cov (symmetric read), folds into Wv -> Mv.
// ---------------------------------------------------------------------------
__global__ __launch_bounds__(256) void attn_kernel(const float* __restrict__ qkv_w,
        const float* __restrict__ temp, float* __restrict__ ws) {
    __shared__ float Wl[192 * 65];
    __shared__ float Cv[64 * 65];
    __shared__ float TQ[64 * 65];
    __shared__ float TK[64 * 65];
    __shared__ float qkb[256];
    __shared__ float qqb[64];
    __shared__ float kkb[64];
    __shared__ float atl[256];
    const int t = threadIdx.x;
    const int e = blockIdx.x >> 3, b = blockIdx.x & 7;
    const float lg = ws[OFF_LOGIT + b * 3 + e];
    if (!(lg > 0.0f)) return;              // gated off: contribution is exactly 0

    for (int idx = t; idx < 12288; idx += 256)
        Wl[(idx >> 6) * 65 + (idx & 63)] = qkv_w[e * 12288 + idx];
    for (int idx = t; idx < 4096; idx += 256) {
        const int r = idx >> 6, c = idx & 63;
        const int rr = r < c ? r : c, cc = r < c ? c : r;   // cov is upper-tri
        Cv[r * 65 + c] = ws[OFF_COV + b * 4096 + rr * 64 + cc];
    }
    __syncthreads();

    {   // TQ = Wq*Cov, TK = Wk*Cov
        const int r = t >> 2, cq = (t & 3) << 4;
        float aq[16], ak[16];
        #pragma unroll
        for (int i = 0; i < 16; ++i) { aq[i] = 0.f; ak[i] = 0.f; }
        for (int c1 = 0; c1 < 64; ++c1) {
            float wq = Wl[r * 65 + c1];
            float wk = Wl[(64 + r) * 65 + c1];
            #pragma unroll
            for (int i = 0; i < 16; ++i) {
                float cv = Cv[c1 * 65 + cq + i];
                aq[i] += wq * cv; ak[i] += wk * cv;
            }
        }
        #pragma unroll
        for (int i = 0; i < 16; ++i) { TQ[r*65 + cq + i] = aq[i]; TK[r*65 + cq + i] = ak[i]; }
    }
    __syncthreads();

    for (int idx = t; idx < 384; idx += 256) {   // per-head gram entries
        const int h = idx / 24, u = idx - h * 24;
        float s = 0.f;
        if (u < 16) {
            const int i = u >> 2, j = u & 3;
            const float* tq = &TQ[(4*h + i) * 65];
            const float* wk = &Wl[(64 + 4*h + j) * 65];
            for (int c = 0; c < 64; ++c) s += tq[c] * wk[c];
            qkb[h * 16 + u] = s;
        } else if (u < 20) {
            const int i = u - 16;
            const float* tq = &TQ[(4*h + i) * 65];
            const float* wq = &Wl[(4*h + i) * 65];
            for (int c = 0; c < 64; ++c) s += tq[c] * wq[c];
            qqb[h * 4 + i] = s;
        } else {
            const int j = u - 20;
            const float* tk = &TK[(4*h + j) * 65];
            const float* wk = &Wl[(64 + 4*h + j) * 65];
            for (int c = 0; c < 64; ++c) s += tk[c] * wk[c];
            kkb[h * 4 + j] = s;
        }
    }
    __syncthreads();

    if (t < 64) {                           // softmax over j (4-wide)
        const int h = t >> 2, i = t & 3;
        const float tp = temp[e * 16 + h];
        const float rq = 1.0f / fmaxf(sqrtf(qqb[h*4 + i]), 1e-12f);
        float lq[4];
        #pragma unroll
        for (int j = 0; j < 4; ++j) {
            float rk = 1.0f / fmaxf(sqrtf(kkb[h*4 + j]), 1e-12f);
            lq[j] = qkb[h*16 + i*4 + j] * rq * rk * tp;
        }
        float m = fmaxf(fmaxf(lq[0], lq[1]), fmaxf(lq[2], lq[3]));
        float ex[4]; float s = 0.f;
        #pragma unroll
        for (int j = 0; j < 4; ++j) { ex[j] = expf(lq[j] - m); s += ex[j]; }
        float inv = 1.0f / s;
        #pragma unroll
        for (int j = 0; j < 4; ++j) atl[h*16 + i*4 + j] = ex[j] * inv;
    }
    __syncthreads();

    // Mv[o][c] = sum_j attn[h(o)][o%4][j] * Wv[4h+j][c]
    float* mv = ws + OFF_MV + (size_t)blockIdx.x * 4096;
    for (int idx = t; idx < 4096; idx += 256) {
        const int o = idx >> 6, c = idx & 63;
        const int h = o >> 2, ii = o & 3;
        float s = 0.f;
        #pragma unroll
        for (int j = 0; j < 4; ++j)
            s += atl[h*16 + ii*4 + j] * Wl[(128 + 4*h + j) * 65 + c];
        mv[idx] = s;
    }
}

// ---------------------------------------------------------------------------
// Kernel 3.5: fold logit*proj*dw(tap)*Mv -> H[b][64][tap*64+c] bf16.
// grid 72 = 8 b x 9 taps, block 256. Zero when no expert active.
// ---------------------------------------------------------------------------
__global__ __launch_bounds__(256) void hbuild_kernel(const float* __restrict__ dw_w,
        const float* __restrict__ proj_w, float* __restrict__ ws) {
    __shared__ float Pl[64 * 65];
    __shared__ float Ml[64 * 65];
    const int t = threadIdx.x;
    const int b = blockIdx.x / 9, tap = blockIdx.x - b * 9;
    const int o = t >> 2, c4 = (t & 3) << 4;
    float s[16];
    #pragma unroll
    for (int i = 0; i < 16; ++i) s[i] = 0.f;
    for (int e = 0; e < 3; ++e) {
        const float lg = ws[OFF_LOGIT + b * 3 + e];
        __syncthreads();
        if (lg > 0.f) {
            for (int idx = t; idx < 4096; idx += 256) {
                const int oo = idx >> 6, mm = idx & 63;
                Pl[oo * 65 + mm] = proj_w[e * 4096 + idx] * dw_w[e * 576 + mm * 9 + tap] * lg;
                Ml[oo * 65 + mm] = ws[OFF_MV + (size_t)(e * 8 + b) * 4096 + idx];
            }
            __syncthreads();
            for (int m = 0; m < 64; ++m) {
                const float wv = Pl[o * 65 + m];
                const float* mr = &Ml[m * 65 + c4];
                #pragma unroll
                for (int i = 0; i < 16; ++i) s[i] += wv * mr[i];
            }
        }
    }
    unsigned short* Hg = (unsigned short*)((char*)ws + OFF_H_BYTES);
    unsigned short* hrow = Hg + (size_t)(b * 64 + o) * 576 + tap * 64 + c4;
    #pragma unroll
    for (int i = 0; i < 16; ++i) hrow[i] = f2bf(s[i]);
}

// ---------------------------------------------------------------------------
// Kernel 4: implicit-GEMM 3x3 conv:  out[b] = sum_tap H[b,tap] @ shift(x[b])
// grid 256 = 8 b x 16 ytiles x 2 xtiles, block 512 (8 waves).
// Tile: M=64 (all out ch) x N=512 px (8 rows x 64 cols), K=576.
// Wave w = output row w: 64x64 per wave, 16 acc frags, 4A+4B b128 reads and
// 16 MFMAs per K-step, 18 steps, no barriers / no global in K-loop.
// LDS: x halo [10 rows][66 cols][64 ch] bf16, 16B-unit XOR-swizzle on col;
//      H [64][584] bf16 (pad 584 -> 2-way max).
// ---------------------------------------------------------------------------
#define XP 4224      // 66*64 ushorts per halo row
#define HP 584

__global__ __launch_bounds__(512, 2) void conv_kernel(const float* __restrict__ x,
        const float* __restrict__ ws, float* __restrict__ out) {
    __shared__ unsigned short xl[10 * XP];     // 84480 B
    __shared__ unsigned short hl[64 * HP];     // 74752 B
    const int t = threadIdx.x;
    const int w = t >> 6, l = t & 63;
    const int bx = blockIdx.x;
    const int b = bx >> 5;
    const int tile = bx & 31;
    const int ty = tile >> 1, tx = tile & 1;
    const int y0 = ty * 8, x0 = tx * 64;
    const float* xb = x + ((size_t)b << 20);

    // ---- stage x halo: lane = channel, stream cols (L1-line reuse) ----
    {
        const int u8 = l >> 3, lo = l & 7;
        for (int rr = w; rr < 10; rr += 8) {
            const int gy = y0 - 1 + rr;
            const bool yok = ((unsigned)gy < 128u);
            const float* src = xb + ((size_t)l << 14) + ((size_t)(yok ? gy : 0) << 7);
            for (int h = 0; h < 66; ++h) {
                const int gx = x0 - 1 + h;
                float v = (yok && ((unsigned)gx < 128u)) ? src[gx] : 0.f;
                xl[rr * XP + h * 64 + ((u8 ^ (h & 7)) << 3) + lo] = f2bf(v);
            }
        }
    }
    // ---- stage H[b] ----
    {
        const unsigned int* hg = (const unsigned int*)((const char*)ws + OFF_H_BYTES)
                               + (size_t)b * 64 * 288;
        const int o = t >> 3, j = t & 7;
        #pragma unroll 4
        for (int m = 0; m < 36; ++m) {
            const unsigned int uv = hg[o * 288 + j * 36 + m];
            *(unsigned int*)&hl[o * HP + j * 72 + 2 * m] = uv;
        }
    }
    __syncthreads();

    f32x4 acc[4][4];
    const f32x4 fz = {0.f, 0.f, 0.f, 0.f};
    #pragma unroll
    for (int mi = 0; mi < 4; ++mi)
        #pragma unroll
        for (int f = 0; f < 4; ++f) acc[mi][f] = fz;

    const int aoff = (l & 15) * HP + (l >> 4) * 8;
    const int bcol = (l & 15) * 64;
    int su8[3][2];                         // swizzled unit offset per (dx+1, s)
    #pragma unroll
    for (int dxi = 0; dxi < 3; ++dxi)
        #pragma unroll
        for (int s = 0; s < 2; ++s)
            su8[dxi][s] = ((s * 4 + (l >> 4)) ^ (((l & 15) + dxi) & 7)) << 3;

    #pragma unroll
    for (int tap = 0; tap < 9; ++tap) {
        const int dy = tap / 3 - 1;
        const int dxi = tap % 3;           // dx + 1
        const int hr = w + 1 + dy;
        #pragma unroll
        for (int s = 0; s < 2; ++s) {
            const int k0 = tap * 64 + s * 32;
            bf16x8 af[4], bfr[4];
            #pragma unroll
            for (int mi = 0; mi < 4; ++mi)
                af[mi] = *(const bf16x8*)&hl[mi * 16 * HP + k0 + aoff];
            #pragma unroll
            for (int f = 0; f < 4; ++f)
                bfr[f] = *(const bf16x8*)&xl[hr * XP + (f * 16 + dxi) * 64 + bcol + su8[dxi][s]];
            #pragma unroll
            for (int mi = 0; mi < 4; ++mi)
                #pragma unroll
                for (int f = 0; f < 4; ++f)
                    acc[mi][f] = __builtin_amdgcn_mfma_f32_16x16x32_bf16(af[mi], bfr[f], acc[mi][f], 0, 0, 0);
        }
    }

    // ---- epilogue: D layout col=lane&15 (pixel), row=(lane>>4)*4+j (channel)
    const int gy = y0 + w;
    float* ob = out + ((size_t)b << 20) + (gy << 7) + x0;
    const int orow = (l >> 4) << 2;
    const int ocol = l & 15;
    #pragma unroll
    for (int mi = 0; mi < 4; ++mi)
        #pragma unroll
        for (int f = 0; f < 4; ++f)
            #pragma unroll
            for (int j = 0; j < 4; ++j)
                ob[((size_t)(mi * 16 + orow + j) << 14) + f * 16 + ocol] = acc[mi][f][j];
}

// ---------------------------------------------------------------------------
extern "C" void kernel_launch(void* const* d_in, const int* in_sizes, int n_in,
                              void* d_out, int out_size, void* d_ws, size_t ws_size,
                              hipStream_t stream) {
    const float* x      = (const float*)d_in[0];
    const float* hidden = (const float*)d_in[1];
    const float* qkv_w  = (const float*)d_in[2];
    const float* dw_w   = (const float*)d_in[3];
    const float* proj_w = (const float*)d_in[4];
    const float* temp   = (const float*)d_in[5];
    const float* r1w    = (const float*)d_in[6];
    const float* r1b    = (const float*)d_in[7];
    const float* r3w    = (const float*)d_in[8];
    const float* r3b    = (const float*)d_in[9];
    float* out = (float*)d_out;
    float* ws  = (float*)d_ws;

    // zero the atomic-accumulated regions (ws is poisoned 0xAA before each call)
    hipMemsetAsync(ws, 0, (size_t)(512 + 32768) * sizeof(float), stream);

    cov_kernel   <<<dim3(256), dim3(256), 0, stream>>>(x, ws);
    route_kernel <<<dim3(1),   dim3(128), 0, stream>>>(hidden, r1w, r1b, r3w, r3b, ws, out);
    attn_kernel  <<<dim3(24),  dim3(256), 0, stream>>>(qkv_w, temp, ws);
    hbuild_kernel<<<dim3(72),  dim3(256), 0, stream>>>(dw_w, proj_w, ws);
    conv_kernel  <<<dim3(256), dim3(512), 0, stream>>>(x, ws, out);
}